// Round 4
// baseline (1142.454 us; speedup 1.0000x reference)
//
#include <hip/hip_runtime.h>
#include <cstddef>

#define NN 50000
#define EE 1600000
#define IN_DIM 512
#define HID 256
#define OUT_DIM 40
#define KSTEPS 10
#define BN_EPS 1e-5f
#define BGRAPH 64
#define ECHUNK (EE / BGRAPH)   // 25000

typedef __attribute__((ext_vector_type(8))) short short8;
typedef __attribute__((ext_vector_type(4))) float f32x4;

__device__ inline unsigned short bf16_rne(float v) {
    union { float f; unsigned u; } c; c.f = v;
    unsigned u = c.u;
    unsigned r = u + 0x7fff + ((u >> 16) & 1);
    return (unsigned short)(r >> 16);
}
__device__ inline float bf16_to_f(unsigned short h) {
    union { unsigned u; float f; } c; c.u = ((unsigned)h) << 16;
    return c.f;
}

// ---------------- phase A: block-private histograms (row-degree + col-count) ----------------
// Block b owns histR[b*NN..], histC[b*NN..] -> atomics never cross blocks/XCDs.
__global__ __launch_bounds__(256) void k_histA(const int* __restrict__ ei,
                                               int* __restrict__ histR,
                                               int* __restrict__ histC) {
    int b = blockIdx.x, tid = threadIdx.x;
    int* hr = histR + (size_t)b * NN;
    int* hc = histC + (size_t)b * NN;
    for (int i = tid; i < NN; i += 256) { hr[i] = 0; hc[i] = 0; }
    __syncthreads();
    int e0 = b * ECHUNK;
    for (int e = e0 + tid; e < e0 + ECHUNK; e += 256) {
        atomicAdd(&hr[ei[e]], 1);
        atomicAdd(&hc[ei[EE + e]], 1);
    }
}

// ---------------- row-degree reduce -> dinv ----------------
__global__ void k_dinv2(const int* __restrict__ histR, float* __restrict__ dinv) {
    int i = blockIdx.x * blockDim.x + threadIdx.x;
    if (i >= NN) return;
    int d = 0;
#pragma unroll 8
    for (int b = 0; b < BGRAPH; ++b) d += histR[(size_t)b * NN + i];
    float fd = d < 1 ? 1.0f : (float)d;
    dinv[i] = 1.0f / sqrtf(fd);
}

// ---------------- per-bin prefix across blocks; histC[b][i] -> prefix, total[i] = sum ----------------
__global__ void k_colsum(int* __restrict__ histC, int* __restrict__ total) {
    int i = blockIdx.x * blockDim.x + threadIdx.x;
    if (i >= NN) return;
    int run = 0;
#pragma unroll 8
    for (int b = 0; b < BGRAPH; ++b) {
        size_t idx = (size_t)b * NN + i;
        int t = histC[idx];
        histC[idx] = run;
        run += t;
    }
    total[i] = run;
}

// ---------------- parallel exclusive scan: total -> ptr ----------------
__global__ __launch_bounds__(1024) void k_scan(const int* __restrict__ total,
                                               int* __restrict__ ptr) {
    __shared__ int wsum[16];
    int tid = threadIdx.x;
    const int CH = (NN + 1023) / 1024;   // 49
    int st = tid * CH;
    int en = st + CH < NN ? st + CH : NN;
    int s = 0;
    for (int i = st; i < en; ++i) s += total[i];
    int lane = tid & 63, w = tid >> 6;
    int v = s;
    for (int d = 1; d < 64; d <<= 1) {
        int t = __shfl_up(v, d);
        if (lane >= d) v += t;
    }
    if (lane == 63) wsum[w] = v;
    __syncthreads();
    if (w == 0) {
        int t = (lane < 16) ? wsum[lane] : 0;
        for (int d = 1; d < 16; d <<= 1) {
            int u = __shfl_up(t, d);
            if (lane >= d) t += u;
        }
        if (lane < 16) wsum[lane] = t;
    }
    __syncthreads();
    int base = (w > 0 ? wsum[w - 1] : 0) + (v - s);
    int run = base;
    for (int i = st; i < en; ++i) {
        ptr[i] = run;
        run += total[i];
    }
    if (tid == 1023) ptr[NN] = run;
}

// ---------------- phase C: scatter via block-private cursors ----------------
__global__ __launch_bounds__(256) void k_scatter2(const int* __restrict__ ei,
                                                  const float* __restrict__ dinv,
                                                  const int* __restrict__ ptr,
                                                  int* __restrict__ histC,
                                                  int2* __restrict__ epack) {
    int b = blockIdx.x, tid = threadIdx.x;
    int* hc = histC + (size_t)b * NN;
    int e0 = b * ECHUNK;
    for (int e = e0 + tid; e < e0 + ECHUNK; e += 256) {
        int r = ei[e];
        int c = ei[EE + e];
        int ofs = atomicAdd(&hc[c], 1);     // block-private -> L2-local
        int2 p;
        p.x = r;
        p.y = __float_as_int(dinv[r] * dinv[c]);
        epack[ptr[c] + ofs] = p;
    }
}

// ---------------- W1 -> bf16 hi/lo split (once per call) ----------------
__global__ void k_w1split(const float* __restrict__ W1, unsigned short* __restrict__ w1h,
                          unsigned short* __restrict__ w1l) {
    int i = blockIdx.x * blockDim.x + threadIdx.x;
    if (i >= HID * IN_DIM) return;
    float v = W1[i];
    unsigned short h = bf16_rne(v);
    unsigned short l = bf16_rne(v - bf16_to_f(h));
    w1h[i] = h;
    w1l[i] = l;
}

// ---------------- GEMM1 via split-bf16 MFMA: h = relu(BN(x @ W1^T + b1)) ----------------
#define BM 64
#define BK 64
__global__ __launch_bounds__(512) void k_gemm1m(const float* __restrict__ x,
                                                const unsigned short* __restrict__ w1h,
                                                const unsigned short* __restrict__ w1l,
                                                const float* __restrict__ b1,
                                                const float* __restrict__ bnw,
                                                const float* __restrict__ bnb,
                                                const float* __restrict__ bnm,
                                                const float* __restrict__ bnv,
                                                float* __restrict__ h) {
    __shared__ __align__(16) unsigned short Ah[BM * BK];
    __shared__ __align__(16) unsigned short Al[BM * BK];
    __shared__ __align__(16) unsigned short Bh[HID * BK];
    __shared__ __align__(16) unsigned short Bl[HID * BK];
    int tid = threadIdx.x;
    int lane = tid & 63;
    int wid = tid >> 6;
    int wm = wid >> 2;
    int wn = wid & 3;
    int brow = blockIdx.x * BM;

    int ra = tid >> 3, ca = (tid & 7) * 8;
    int rb = tid >> 1, cb = (tid & 1) * 32;

    bool rok = (brow + ra) < NN;
    const float* xa = x + (size_t)(brow + ra) * IN_DIM + ca;
    const unsigned short* bhp = w1h + (size_t)rb * IN_DIM + cb;
    const unsigned short* blp = w1l + (size_t)rb * IN_DIM + cb;

    int abyte = (ra * BK + ca) * 2; abyte ^= (ra & 7) << 4;
    int bbyte0 = (rb * BK + cb) * 2;
    int bsw = (rb & 7) << 4;

    f32x4 acc[2][4];
#pragma unroll
    for (int i = 0; i < 2; ++i)
#pragma unroll
        for (int j = 0; j < 4; ++j) acc[i][j] = (f32x4){0.f, 0.f, 0.f, 0.f};

    int frow_a = wm * 32 + (lane & 15);
    int frow_b = wn * 64 + (lane & 15);
    int fk = (lane >> 4) * 16;

    for (int kt = 0; kt < IN_DIM; kt += BK) {
        float4 v0 = make_float4(0.f, 0.f, 0.f, 0.f), v1 = v0;
        if (rok) {
            v0 = *(const float4*)(xa + kt);
            v1 = *(const float4*)(xa + kt + 4);
        }
        short8 gb_h[4], gb_l[4];
#pragma unroll
        for (int q = 0; q < 4; ++q) {
            gb_h[q] = *(const short8*)(bhp + kt + q * 8);
            gb_l[q] = *(const short8*)(blp + kt + q * 8);
        }
        __syncthreads();
        union { unsigned short u[8]; short8 v; } uh, ul;
        float vv[8] = {v0.x, v0.y, v0.z, v0.w, v1.x, v1.y, v1.z, v1.w};
#pragma unroll
        for (int j = 0; j < 8; ++j) {
            unsigned short hh = bf16_rne(vv[j]);
            uh.u[j] = hh;
            ul.u[j] = bf16_rne(vv[j] - bf16_to_f(hh));
        }
        *(short8*)((char*)Ah + abyte) = uh.v;
        *(short8*)((char*)Al + abyte) = ul.v;
#pragma unroll
        for (int q = 0; q < 4; ++q) {
            int bb = (bbyte0 + q * 16) ^ bsw;
            *(short8*)((char*)Bh + bb) = gb_h[q];
            *(short8*)((char*)Bl + bb) = gb_l[q];
        }
        __syncthreads();

#pragma unroll
        for (int kk = 0; kk < 2; ++kk) {
            short8 afh[2], afl[2];
#pragma unroll
            for (int mi = 0; mi < 2; ++mi) {
                int row = frow_a + mi * 16;
                int byte = (row * BK * 2 + kk * 64 + fk) ^ ((row & 7) << 4);
                afh[mi] = *(short8*)((char*)Ah + byte);
                afl[mi] = *(short8*)((char*)Al + byte);
            }
#pragma unroll
            for (int ni = 0; ni < 4; ++ni) {
                int row = frow_b + ni * 16;
                int byte = (row * BK * 2 + kk * 64 + fk) ^ ((row & 7) << 4);
                short8 bh = *(short8*)((char*)Bh + byte);
                short8 bl = *(short8*)((char*)Bl + byte);
#pragma unroll
                for (int mi = 0; mi < 2; ++mi) {
                    acc[mi][ni] = __builtin_amdgcn_mfma_f32_16x16x32_bf16(afh[mi], bh, acc[mi][ni], 0, 0, 0);
                    acc[mi][ni] = __builtin_amdgcn_mfma_f32_16x16x32_bf16(afl[mi], bh, acc[mi][ni], 0, 0, 0);
                    acc[mi][ni] = __builtin_amdgcn_mfma_f32_16x16x32_bf16(afh[mi], bl, acc[mi][ni], 0, 0, 0);
                }
            }
        }
    }

    int cbase = wn * 64 + (lane & 15);
    float scl[4], off[4];
#pragma unroll
    for (int ni = 0; ni < 4; ++ni) {
        int c = cbase + ni * 16;
        float s = bnw[c] * rsqrtf(bnv[c] + BN_EPS);
        scl[ni] = s;
        off[ni] = (b1[c] - bnm[c]) * s + bnb[c];
    }
#pragma unroll
    for (int mi = 0; mi < 2; ++mi) {
        int r0 = brow + wm * 32 + mi * 16 + ((lane >> 4) << 2);
#pragma unroll
        for (int ni = 0; ni < 4; ++ni) {
            int c = cbase + ni * 16;
#pragma unroll
            for (int j = 0; j < 4; ++j) {
                int r = r0 + j;
                if (r < NN) {
                    float v = acc[mi][ni][j] * scl[ni] + off[ni];
                    h[(size_t)r * HID + c] = v > 0.f ? v : 0.f;
                }
            }
        }
    }
}

// ---------------- GEMM2: z = h @ W2^T + b2; ping = z; out = gamma0 * z ----------------
__global__ __launch_bounds__(256) void k_gemm2(const float* __restrict__ h,
                                               const float* __restrict__ W2,
                                               const float* __restrict__ b2,
                                               const float* __restrict__ gamma,
                                               float* __restrict__ ping,
                                               float* __restrict__ out) {
    __shared__ float W2T[HID * OUT_DIM];
    int tid = threadIdx.x;
    for (int i = tid; i < HID * OUT_DIM; i += 256) {
        int o = i / HID;
        int k = i - o * HID;
        W2T[k * OUT_DIM + o] = W2[i];
    }
    __syncthreads();
    int n = blockIdx.x * 256 + tid;
    if (n >= NN) return;

    float4 acc[10];
#pragma unroll
    for (int o4 = 0; o4 < 10; ++o4) acc[o4] = *(const float4*)&b2[o4 * 4];

    const float4* hr = (const float4*)(h + (size_t)n * HID);
    const float4* wt = (const float4*)W2T;
    for (int j = 0; j < HID / 4; ++j) {
        float4 hv = hr[j];
#pragma unroll
        for (int c = 0; c < 4; ++c) {
            float hk = (c == 0) ? hv.x : (c == 1) ? hv.y : (c == 2) ? hv.z : hv.w;
            const float4* wr = wt + (size_t)(j * 4 + c) * 10;
#pragma unroll
            for (int o4 = 0; o4 < 10; ++o4) {
                float4 w = wr[o4];
                acc[o4].x += hk * w.x;
                acc[o4].y += hk * w.y;
                acc[o4].z += hk * w.z;
                acc[o4].w += hk * w.w;
            }
        }
    }
    float g0 = gamma[0];
    float4* pp = (float4*)(ping + (size_t)n * OUT_DIM);
    float4* op = (float4*)(out + (size_t)n * OUT_DIM);
#pragma unroll
    for (int o4 = 0; o4 < 10; ++o4) {
        pp[o4] = acc[o4];
        float4 g;
        g.x = g0 * acc[o4].x; g.y = g0 * acc[o4].y;
        g.z = g0 * acc[o4].z; g.w = g0 * acc[o4].w;
        op[o4] = g;
    }
}

// ---------------- one propagation step ----------------
__global__ __launch_bounds__(256) void k_spmm(const int* __restrict__ ptr,
                                              const int2* __restrict__ epack,
                                              const float* __restrict__ cur,
                                              float* __restrict__ nxt,
                                              float* __restrict__ out,
                                              const float* __restrict__ gamma, int k) {
    int wave = (blockIdx.x * blockDim.x + threadIdx.x) >> 6;
    int lane = threadIdx.x & 63;
    if (wave >= NN) return;
    int e0 = ptr[wave];
    int e1 = ptr[wave + 1];
    if (lane < OUT_DIM) {
        float a0 = 0.f, a1 = 0.f, a2 = 0.f, a3 = 0.f;
        int e = e0;
        for (; e + 3 < e1; e += 4) {
            int2 p0 = epack[e], p1 = epack[e + 1], p2 = epack[e + 2], p3 = epack[e + 3];
            a0 += __int_as_float(p0.y) * cur[(size_t)p0.x * OUT_DIM + lane];
            a1 += __int_as_float(p1.y) * cur[(size_t)p1.x * OUT_DIM + lane];
            a2 += __int_as_float(p2.y) * cur[(size_t)p2.x * OUT_DIM + lane];
            a3 += __int_as_float(p3.y) * cur[(size_t)p3.x * OUT_DIM + lane];
        }
        for (; e < e1; ++e) {
            int2 p = epack[e];
            a0 += __int_as_float(p.y) * cur[(size_t)p.x * OUT_DIM + lane];
        }
        float acc = (a0 + a1) + (a2 + a3);
        nxt[(size_t)wave * OUT_DIM + lane] = acc;
        out[(size_t)wave * OUT_DIM + lane] += gamma[k] * acc;
    }
}

extern "C" void kernel_launch(void* const* d_in, const int* in_sizes, int n_in,
                              void* d_out, int out_size, void* d_ws, size_t ws_size,
                              hipStream_t stream) {
    const float* x   = (const float*)d_in[0];
    const int*   ei  = (const int*)d_in[1];
    const float* W1  = (const float*)d_in[2];
    const float* b1  = (const float*)d_in[3];
    const float* bnw = (const float*)d_in[4];
    const float* bnb = (const float*)d_in[5];
    const float* bnm = (const float*)d_in[6];
    const float* bnv = (const float*)d_in[7];
    const float* W2  = (const float*)d_in[8];
    const float* b2  = (const float*)d_in[9];
    const float* gamma = (const float*)d_in[10];
    float* out = (float*)d_out;

    char* ws = (char*)d_ws;
    const size_t A = 256;
    auto pad = [&](size_t b) { return (b + A - 1) / A * A; };
    size_t off = 0;
    int*   ptr    = (int*)  (ws + off); off += pad((size_t)(NN + 1) * 4);
    int*   total  = (int*)  (ws + off); off += pad((size_t)NN * 4);
    float* dinv   = (float*)(ws + off); off += pad((size_t)NN * 4);
    int2*  epack  = (int2*) (ws + off); off += pad((size_t)EE * 8);
    float* h      = (float*)(ws + off); off += pad((size_t)NN * HID * 4);
    float* ping   = (float*)(ws + off); off += pad((size_t)NN * OUT_DIM * 4);
    float* pong   = (float*)(ws + off); off += pad((size_t)NN * OUT_DIM * 4);
    unsigned short* w1h = (unsigned short*)(ws + off); off += pad((size_t)HID * IN_DIM * 2);
    unsigned short* w1l = (unsigned short*)(ws + off); off += pad((size_t)HID * IN_DIM * 2);

    // histR/histC alias h (h is written only later, by gemm1m)
    int* histR = (int*)h;                                   // BGRAPH*NN ints = 12.8 MB
    int* histC = (int*)((char*)h + (size_t)BGRAPH * NN * 4); // next 12.8 MB

    // graph structure (block-private two-phase counting sort; no global contention)
    k_histA<<<BGRAPH, 256, 0, stream>>>(ei, histR, histC);
    k_dinv2<<<(NN + 255) / 256, 256, 0, stream>>>(histR, dinv);
    k_colsum<<<(NN + 255) / 256, 256, 0, stream>>>(histC, total);
    k_scan<<<1, 1024, 0, stream>>>(total, ptr);
    k_scatter2<<<BGRAPH, 256, 0, stream>>>(ei, dinv, ptr, histC, epack);

    // MLP
    k_w1split<<<(HID * IN_DIM + 255) / 256, 256, 0, stream>>>(W1, w1h, w1l);
    k_gemm1m<<<(NN + BM - 1) / BM, 512, 0, stream>>>(x, w1h, w1l, b1, bnw, bnb, bnm, bnv, h);
    k_gemm2<<<(NN + 255) / 256, 256, 0, stream>>>(h, W2, b2, gamma, ping, out);

    // K propagation steps, ping-pong
    float* cur = ping;
    float* nxt = pong;
    for (int k = 1; k <= KSTEPS; ++k) {
        k_spmm<<<(NN * 64 + 255) / 256, 256, 0, stream>>>(ptr, epack, cur, nxt, out, gamma, k);
        float* t = cur; cur = nxt; nxt = t;
    }
}